// Round 2
// baseline (2776.807 us; speedup 1.0000x reference)
//
#include <hip/hip_runtime.h>
#include <stdint.h>

typedef __attribute__((ext_vector_type(8))) short short8;
typedef __attribute__((ext_vector_type(4))) float f32x4;
typedef __attribute__((ext_vector_type(4))) unsigned u32x4;

#define T_SZ 512

// ws layout (bytes)
#define XP_OFF    0ull                 // xp (bf16): 16384*4096*2 = 134217728
#define UPERM_OFF 134217728ull         // Uperm (bf16): 8 MB
#define WPERM_OFF 142606336ull         // Wperm (bf16): 4 MB
#define HBUF_OFF  146800640ull         // hbuf: 4 slabs x 32 x 1024 dwords = 512 KB

static __device__ __forceinline__ float b2f(unsigned short u) {
  unsigned v = ((unsigned)u) << 16;
  return __builtin_bit_cast(float, v);
}
static __device__ __forceinline__ unsigned short f2b(float f) {
  unsigned u = __builtin_bit_cast(unsigned, f);
  u += 0x7fffu + ((u >> 16) & 1u);   // RNE
  return (unsigned short)(u >> 16);
}
static __device__ __forceinline__ float sigm(float x) {
  return 1.0f / (1.0f + __expf(-x));
}
static __device__ __forceinline__ float tanh_f(float x) {
  return 1.0f - 2.0f / (__expf(2.0f * x) + 1.0f);
}

// ---- one-time permutation of U (f32 -> bf16) into MFMA B-fragment layout ----
// Fragment table indexed by [cg(64)][kq(4)][g(4)][kk(8)]; consumers compute
// the flat index for whatever (k, n) tiling they use.
__global__ void permute_U(const float* __restrict__ U, unsigned short* __restrict__ Up) {
  int t = blockIdx.x * 256 + threadIdx.x;        // 524288 threads
  int l = t & 63;
  int F = t >> 6;                                 // 8192 frags
  int kk = F & 7, g = (F >> 3) & 3, kq = (F >> 5) & 3, cg = F >> 7;
  int k0 = kq * 256 + kk * 32 + (l >> 4) * 8;
  int n  = g * 1024 + cg * 16 + (l & 15);
  unsigned short v[8];
#pragma unroll
  for (int j = 0; j < 8; j++) v[j] = f2b(U[(size_t)(k0 + j) * 4096 + n]);
  unsigned short* dst = Up + (size_t)t * 8;
#pragma unroll
  for (int j = 0; j < 8; j++) dst[j] = v[j];
}

__global__ void permute_W(const float* __restrict__ W, unsigned short* __restrict__ Wp) {
  int t = blockIdx.x * 256 + threadIdx.x;        // 262144 threads
  int l = t & 63;
  int F = t >> 6;                                 // 4096 frags
  int kk = F & 15, nt = F >> 4;
  int k0 = kk * 32 + (l >> 4) * 8;
  int n  = nt * 16 + (l & 15);
  unsigned short v[8];
#pragma unroll
  for (int j = 0; j < 8; j++) v[j] = f2b(W[(size_t)(k0 + j) * 4096 + n]);
  unsigned short* dst = Wp + (size_t)t * 8;
#pragma unroll
  for (int j = 0; j < 8; j++) dst[j] = v[j];
}

// hbuf: 4 slabs x 32768 dwords. slab 0 = (h=0, tag=0); slabs 1..3 = tag 0xFFFF.
__global__ void init_hbuf(unsigned* __restrict__ hbuf) {
  int t = blockIdx.x * 256 + threadIdx.x;        // 131072 threads
  hbuf[t] = (t < 32768) ? 0u : 0xFFFFu;
}

// ---- Phase B: xp[m][n] = X[m][:] @ W[:][n] + b[n], M=16384 N=4096 K=512 ----
__global__ __launch_bounds__(256) void xproj_gemm(
    const float* __restrict__ X,
    const unsigned short* __restrict__ Wp,
    const float* __restrict__ bias,
    unsigned short* __restrict__ xp) {
  const int tid = threadIdx.x;
  const int l = tid & 63;
  const int w = tid >> 6;
  const int wr = w >> 1, wc = w & 1;
  const int bn = blockIdx.x;   // 32
  const int bm = blockIdx.y;   // 128
  const int quad = l >> 4, lane16 = l & 15;
  __shared__ unsigned short lA[128 * 72];

  f32x4 acc[4][4];
#pragma unroll
  for (int i = 0; i < 4; i++)
#pragma unroll
    for (int j = 0; j < 4; j++) acc[i][j] = (f32x4){0.f, 0.f, 0.f, 0.f};

  const int m0 = bm * 128;
  const int sr = tid >> 3;
  const int sc = (tid & 7) * 8;

  for (int ks = 0; ks < 8; ks++) {
    __syncthreads();
#pragma unroll
    for (int it = 0; it < 4; it++) {
      int row = sr + it * 32;
      const float* src = X + (size_t)(m0 + row) * 512 + ks * 64 + sc;
      float4 a = *(const float4*)(src);
      float4 c = *(const float4*)(src + 4);
      unsigned short tmp[8] = {f2b(a.x), f2b(a.y), f2b(a.z), f2b(a.w),
                               f2b(c.x), f2b(c.y), f2b(c.z), f2b(c.w)};
      *(int4*)(lA + row * 72 + sc) = *(const int4*)tmp;
    }
    __syncthreads();
#pragma unroll
    for (int kk = 0; kk < 2; kk++) {
      short8 af[4], bf[4];
#pragma unroll
      for (int i = 0; i < 4; i++)
        af[i] = *(const short8*)(lA + (wr * 64 + i * 16 + lane16) * 72 + kk * 32 + quad * 8);
#pragma unroll
      for (int j = 0; j < 4; j++) {
        int F = (bn * 8 + wc * 4 + j) * 16 + ks * 2 + kk;
        bf[j] = *(const short8*)(Wp + (size_t)(F * 64 + l) * 8);
      }
#pragma unroll
      for (int i = 0; i < 4; i++)
#pragma unroll
        for (int j = 0; j < 4; j++)
          acc[i][j] = __builtin_amdgcn_mfma_f32_16x16x32_bf16(af[i], bf[j], acc[i][j], 0, 0, 0);
    }
  }
#pragma unroll
  for (int j = 0; j < 4; j++) {
    int n = bn * 128 + wc * 64 + j * 16 + lane16;
    float bj = bias[n];
#pragma unroll
    for (int i = 0; i < 4; i++)
#pragma unroll
      for (int r = 0; r < 4; r++) {
        int m = m0 + wr * 64 + i * 16 + quad * 4 + r;
        xp[(size_t)m * 4096 + n] = f2b(acc[i][j][r] + bj);
      }
  }
}

// ---- Phase C: persistent recurrent kernel — self-validating h transport ----
// Restructured vs prev round: 64 blocks x 512 threads (8 waves, k-eighth
// split). Each block covers 16 batches x 32 h-cols -> teams (all-to-all
// groups) shrink 64 -> 32 blocks, and machine-wide spin volume per retry
// pass halves (8 MB -> 4 MB), attacking both the LLC-broadcast bandwidth
// and the straggler-max quantization identified in round 1.
// h element = dword (h_bf16<<16 | step_tag), stored write-through (relaxed
// agent atomic), consumed by pipelined sc0sc1 dwordx4 loads + single wait +
// tag validation (per-dword atomicity is the only requirement).
__global__ __launch_bounds__(512, 1) void lstm_rec(
    const unsigned short* __restrict__ xp,
    const unsigned short* __restrict__ Up,
    unsigned* __restrict__ hbuf,         // [4][32][1024] dwords
    float* __restrict__ out) {           // [32][512][1024] f32
  const int tid = threadIdx.x;           // 0..511
  const int l = tid & 63;
  const int kq = tid >> 6;               // wave = k-eighth (0..7)
  const int bid = blockIdx.x;            // 0..63
  const int rg = bid >> 5;               // row-group / batch-half (0..1)
  const int cgrp = bid & 31;             // 32-col group (0..31)
  const int quad = l >> 4, lane16 = l & 15;

  __shared__ float zbuf[2][8][8][16][17];   // [p][kq][tile=cg2*4+g][b][col]

  // preload B fragments (U slice): 2 col-halves x 4 gates x 4 k-frags x 16B
  short8 bfr[2][4][4];
#pragma unroll
  for (int cg2 = 0; cg2 < 2; cg2++)
#pragma unroll
    for (int g = 0; g < 4; g++)
#pragma unroll
      for (int kk = 0; kk < 4; kk++) {
        int cg_old = cgrp * 2 + cg2;          // 16-col group in U table
        int kq_old = kq >> 1;                 // k-quarter in U table
        int kk_old = (kq & 1) * 4 + kk;       // 32-k frag within quarter
        int F = ((cg_old * 4 + kq_old) * 4 + g) * 8 + kk_old;
        bfr[cg2][g][kk] = *(const short8*)(Up + (size_t)(F * 64 + l) * 8);
      }

  float c_st = 0.0f;
  const int bl = tid >> 5;               // 0..15 batch within half
  const int jj = tid & 31;               // 0..31 h-col within group
  const int cg2e = jj >> 4;              // elementwise col-half
  const int ce = jj & 15;
  const int bglob = rg * 16 + bl;

  // consumer base: row = batch (rg*16+lane16), k-eighth kq (dword units)
  const unsigned rowoff = (unsigned)(rg * 16 + lane16) * 1024 + (unsigned)kq * 128;
  // producer store slot (dword units, within slab)
  const unsigned stoff = (unsigned)bglob * 1024 + (unsigned)cgrp * 32 + jj;

  // xp(0) preload (normal cached; produced by earlier dispatch)
  const unsigned short* xpbase =
      xp + (size_t)bglob * T_SZ * 4096 + (size_t)cgrp * 32 + jj;
  unsigned short xr0 = xpbase[0];
  unsigned short xr1 = xpbase[1024];
  unsigned short xr2 = xpbase[2048];
  unsigned short xr3 = xpbase[3072];

#pragma unroll 1
  for (int t = 0; t < T_SZ; t++) {
    // ---- consume h(t): pipelined loads, single wait, then tag-validate ----
    const unsigned tag = (unsigned)t;
    const unsigned* hb32 = hbuf + (size_t)(t & 3) * 32768 + rowoff;
    short8 af[4];
    unsigned pend = 0xFu;                        // wave-uniform frag bitmask
    while (pend) {
      u32x4 ra[4], rb[4];
#pragma unroll
      for (int f = 0; f < 4; f++) {
        if (pend & (1u << f)) {
          const unsigned* p = hb32 + f * 32 + quad * 8;
          asm volatile("global_load_dwordx4 %0, %1, off sc0 sc1"
                       : "=v"(ra[f]) : "v"(p));
          asm volatile("global_load_dwordx4 %0, %1, off offset:16 sc0 sc1"
                       : "=v"(rb[f]) : "v"(p));
        }
      }
      asm volatile("s_waitcnt vmcnt(0)" ::: "memory");
      __builtin_amdgcn_sched_barrier(0);
      unsigned np = pend;
#pragma unroll
      for (int f = 0; f < 4; f++) {
        if (pend & (1u << f)) {
          u32x4 a = ra[f], b = rb[f];
          unsigned bad = ((a[0] ^ tag) | (a[1] ^ tag) | (a[2] ^ tag) | (a[3] ^ tag) |
                          (b[0] ^ tag) | (b[1] ^ tag) | (b[2] ^ tag) | (b[3] ^ tag)) & 0xFFFFu;
          if (__ballot(bad != 0u) == 0ull) {
            np &= ~(1u << f);
            u32x4 v = {(a[0] >> 16) | (a[1] & 0xFFFF0000u),
                       (a[2] >> 16) | (a[3] & 0xFFFF0000u),
                       (b[0] >> 16) | (b[1] & 0xFFFF0000u),
                       (b[2] >> 16) | (b[3] & 0xFFFF0000u)};
            af[f] = __builtin_bit_cast(short8, v);
          }
        }
      }
      pend = np;
      if (pend) __builtin_amdgcn_s_sleep(1);
    }

    // ---- z partial GEMM: wave kq covers k in [kq*128, kq*128+128) ----
    f32x4 acc[2][4];
#pragma unroll
    for (int cg2 = 0; cg2 < 2; cg2++)
#pragma unroll
      for (int g = 0; g < 4; g++) acc[cg2][g] = (f32x4){0.f, 0.f, 0.f, 0.f};
#pragma unroll
    for (int kk = 0; kk < 4; kk++) {
#pragma unroll
      for (int cg2 = 0; cg2 < 2; cg2++)
#pragma unroll
        for (int g = 0; g < 4; g++)
          acc[cg2][g] = __builtin_amdgcn_mfma_f32_16x16x32_bf16(af[kk], bfr[cg2][g][kk], acc[cg2][g], 0, 0, 0);
    }
    const int p = t & 1;
#pragma unroll
    for (int cg2 = 0; cg2 < 2; cg2++)
#pragma unroll
      for (int g = 0; g < 4; g++)
#pragma unroll
        for (int r = 0; r < 4; r++)
          zbuf[p][kq][cg2 * 4 + g][quad * 4 + r][lane16] = acc[cg2][g][r];
    __syncthreads();                 // the ONLY barrier per step

    // ---- elementwise: thread -> (batch bl, h-col jj) ----
    float z0 = b2f(xr0);
    float z1 = b2f(xr1);
    float z2 = b2f(xr2);
    float z3 = b2f(xr3);
#pragma unroll
    for (int q8 = 0; q8 < 8; q8++) {
      z0 += zbuf[p][q8][cg2e * 4 + 0][bl][ce];
      z1 += zbuf[p][q8][cg2e * 4 + 1][bl][ce];
      z2 += zbuf[p][q8][cg2e * 4 + 2][bl][ce];
      z3 += zbuf[p][q8][cg2e * 4 + 3][bl][ce];
    }
    float ig = sigm(z0);
    float fg = sigm(z1);
    float gg = tanh_f(z2);
    float og = sigm(z3);
    c_st = fg * c_st + ig * gg;
    float h = og * tanh_f(c_st);

    // ---- publish h(t+1): tagged dword, write-through, no ordering needed ----
    unsigned tagged = ((unsigned)f2b(h) << 16) | (unsigned)(t + 1);
    __hip_atomic_store(hbuf + (size_t)((t + 1) & 3) * 32768 + stoff, tagged,
                       __ATOMIC_RELAXED, __HIP_MEMORY_SCOPE_AGENT);

    // tail (overlaps other blocks' progress): out store + xp(t+1) prefetch
    out[((size_t)bglob * T_SZ + t) * 1024 + cgrp * 32 + jj] = h;
    {
      int tn = (t + 1 < T_SZ) ? t + 1 : t;
      const unsigned short* xpn = xpbase + (size_t)tn * 4096;
      xr0 = xpn[0];
      xr1 = xpn[1024];
      xr2 = xpn[2048];
      xr3 = xpn[3072];
    }
  }
}

extern "C" void kernel_launch(void* const* d_in, const int* in_sizes, int n_in,
                              void* d_out, int out_size, void* d_ws, size_t ws_size,
                              hipStream_t stream) {
  const float* X    = (const float*)d_in[0];  // [32][512][512]  f32
  const float* W    = (const float*)d_in[1];  // [512][4096]     f32
  const float* U    = (const float*)d_in[2];  // [1024][4096]    f32
  const float* bias = (const float*)d_in[3];  // [4096]          f32
  float* out = (float*)d_out;                 // [32][512][1024] f32

  char* ws = (char*)d_ws;
  unsigned short* xp   = (unsigned short*)(ws + XP_OFF);
  unsigned short* Up   = (unsigned short*)(ws + UPERM_OFF);
  unsigned short* Wp   = (unsigned short*)(ws + WPERM_OFF);
  unsigned*       hbuf = (unsigned*)(ws + HBUF_OFF);

  hipLaunchKernelGGL(permute_U, dim3(2048), dim3(256), 0, stream, U, Up);
  hipLaunchKernelGGL(permute_W, dim3(1024), dim3(256), 0, stream, W, Wp);
  hipLaunchKernelGGL(init_hbuf, dim3(512), dim3(256), 0, stream, hbuf);
  hipLaunchKernelGGL(xproj_gemm, dim3(32, 128), dim3(256), 0, stream, X, Wp, bias, xp);
  hipLaunchKernelGGL(lstm_rec, dim3(64), dim3(512), 0, stream, xp, Up, hbuf, out);
}

// Round 3
// 2455.458 us; speedup vs baseline: 1.1309x; 1.1309x over previous
//
#include <hip/hip_runtime.h>
#include <stdint.h>

typedef __attribute__((ext_vector_type(8))) short short8;
typedef __attribute__((ext_vector_type(4))) float f32x4;
typedef __attribute__((ext_vector_type(4))) unsigned u32x4;

#define T_SZ 512

// ws layout (bytes)
#define XP_OFF    0ull                 // xp (bf16): 16384*4096*2 = 134217728
#define UPERM_OFF 134217728ull         // Uperm (bf16): 8 MB
#define WPERM_OFF 142606336ull         // Wperm (bf16): 4 MB
#define HBUF_OFF  146800640ull         // hbuf: 4 slabs x 32 x 1024 dwords = 512 KB
#define FLAGS_OFF 147324928ull         // flags: 2 teams x 64 producers dwords

static __device__ __forceinline__ float b2f(unsigned short u) {
  unsigned v = ((unsigned)u) << 16;
  return __builtin_bit_cast(float, v);
}
static __device__ __forceinline__ unsigned short f2b(float f) {
  unsigned u = __builtin_bit_cast(unsigned, f);
  u += 0x7fffu + ((u >> 16) & 1u);   // RNE
  return (unsigned short)(u >> 16);
}
static __device__ __forceinline__ float sigm(float x) {
  return 1.0f / (1.0f + __expf(-x));
}
static __device__ __forceinline__ float tanh_f(float x) {
  return 1.0f - 2.0f / (__expf(2.0f * x) + 1.0f);
}

// ---- one-time permutation of U (f32 -> bf16) into MFMA B-fragment layout ----
__global__ void permute_U(const float* __restrict__ U, unsigned short* __restrict__ Up) {
  int t = blockIdx.x * 256 + threadIdx.x;        // 524288 threads
  int l = t & 63;
  int F = t >> 6;                                 // 8192 frags
  int kk = F & 7, g = (F >> 3) & 3, kq = (F >> 5) & 3, cg = F >> 7;
  int k0 = kq * 256 + kk * 32 + (l >> 4) * 8;
  int n  = g * 1024 + cg * 16 + (l & 15);
  unsigned short v[8];
#pragma unroll
  for (int j = 0; j < 8; j++) v[j] = f2b(U[(size_t)(k0 + j) * 4096 + n]);
  unsigned short* dst = Up + (size_t)t * 8;
#pragma unroll
  for (int j = 0; j < 8; j++) dst[j] = v[j];
}

__global__ void permute_W(const float* __restrict__ W, unsigned short* __restrict__ Wp) {
  int t = blockIdx.x * 256 + threadIdx.x;        // 262144 threads
  int l = t & 63;
  int F = t >> 6;                                 // 4096 frags
  int kk = F & 15, nt = F >> 4;
  int k0 = kk * 32 + (l >> 4) * 8;
  int n  = nt * 16 + (l & 15);
  unsigned short v[8];
#pragma unroll
  for (int j = 0; j < 8; j++) v[j] = f2b(W[(size_t)(k0 + j) * 4096 + n]);
  unsigned short* dst = Wp + (size_t)t * 8;
#pragma unroll
  for (int j = 0; j < 8; j++) dst[j] = v[j];
}

// hbuf: 4 slabs x 32768 dwords. slab 0 = (h=0, tag=0); slabs 1..3 = tag 0xFFFF.
// flags: 128 dwords = latest step published by each producer block, init 0.
__global__ void init_hbuf(unsigned* __restrict__ hbuf, unsigned* __restrict__ flags) {
  int t = blockIdx.x * 256 + threadIdx.x;        // 513*256 threads
  if (t < 131072) hbuf[t] = (t < 32768) ? 0u : 0xFFFFu;
  else if (t < 131072 + 128) flags[t - 131072] = 0u;
}

// ---- Phase B: xp[m][n] = X[m][:] @ W[:][n] + b[n], M=16384 N=4096 K=512 ----
__global__ __launch_bounds__(256) void xproj_gemm(
    const float* __restrict__ X,
    const unsigned short* __restrict__ Wp,
    const float* __restrict__ bias,
    unsigned short* __restrict__ xp) {
  const int tid = threadIdx.x;
  const int l = tid & 63;
  const int w = tid >> 6;
  const int wr = w >> 1, wc = w & 1;
  const int bn = blockIdx.x;   // 32
  const int bm = blockIdx.y;   // 128
  const int quad = l >> 4, lane16 = l & 15;
  __shared__ unsigned short lA[128 * 72];

  f32x4 acc[4][4];
#pragma unroll
  for (int i = 0; i < 4; i++)
#pragma unroll
    for (int j = 0; j < 4; j++) acc[i][j] = (f32x4){0.f, 0.f, 0.f, 0.f};

  const int m0 = bm * 128;
  const int sr = tid >> 3;
  const int sc = (tid & 7) * 8;

  for (int ks = 0; ks < 8; ks++) {
    __syncthreads();
#pragma unroll
    for (int it = 0; it < 4; it++) {
      int row = sr + it * 32;
      const float* src = X + (size_t)(m0 + row) * 512 + ks * 64 + sc;
      float4 a = *(const float4*)(src);
      float4 c = *(const float4*)(src + 4);
      unsigned short tmp[8] = {f2b(a.x), f2b(a.y), f2b(a.z), f2b(a.w),
                               f2b(c.x), f2b(c.y), f2b(c.z), f2b(c.w)};
      *(int4*)(lA + row * 72 + sc) = *(const int4*)tmp;
    }
    __syncthreads();
#pragma unroll
    for (int kk = 0; kk < 2; kk++) {
      short8 af[4], bf[4];
#pragma unroll
      for (int i = 0; i < 4; i++)
        af[i] = *(const short8*)(lA + (wr * 64 + i * 16 + lane16) * 72 + kk * 32 + quad * 8);
#pragma unroll
      for (int j = 0; j < 4; j++) {
        int F = (bn * 8 + wc * 4 + j) * 16 + ks * 2 + kk;
        bf[j] = *(const short8*)(Wp + (size_t)(F * 64 + l) * 8);
      }
#pragma unroll
      for (int i = 0; i < 4; i++)
#pragma unroll
        for (int j = 0; j < 4; j++)
          acc[i][j] = __builtin_amdgcn_mfma_f32_16x16x32_bf16(af[i], bf[j], acc[i][j], 0, 0, 0);
    }
  }
#pragma unroll
  for (int j = 0; j < 4; j++) {
    int n = bn * 128 + wc * 64 + j * 16 + lane16;
    float bj = bias[n];
#pragma unroll
    for (int i = 0; i < 4; i++)
#pragma unroll
      for (int r = 0; r < 4; r++) {
        int m = m0 + wr * 64 + i * 16 + quad * 4 + r;
        xp[(size_t)m * 4096 + n] = f2b(acc[i][j][r] + bj);
      }
  }
}

// ---- Phase C: persistent recurrent kernel — self-validating h transport ----
// r1 topology (128 blocks x 256 thr; proven fastest) + producer flags.
// h element = dword (h_bf16<<16 | step_tag), write-through relaxed agent
// store; consumer pass 1 loads data speculatively (fast path). On a stale
// tag it falls into a CHEAP flag gate: 64 lanes read the team's 64 producer
// flags with one coalesced dword load (256 B/pass instead of 16 KB/pass),
// spin until all >= t, then reload data once. Flags are a HINT only —
// correctness still rests entirely on per-dword tag validation, so no
// fences / ordering between h stores and the flag store are needed.
__global__ __launch_bounds__(256, 1) void lstm_rec(
    const unsigned short* __restrict__ xp,
    const unsigned short* __restrict__ Up,
    unsigned* __restrict__ hbuf,         // [4][32][1024] dwords
    unsigned* __restrict__ flags,        // [2][64] dwords
    float* __restrict__ out) {           // [32][512][1024] f32
  const int tid = threadIdx.x;
  const int l = tid & 63;
  const int kq = tid >> 6;           // wave = K-quarter
  const int bid = blockIdx.x;        // 0..127
  const int mh = bid >> 6;           // team (batch half)
  const int cg = bid & 63;           // h-col group
  const int quad = l >> 4, lane16 = l & 15;

  // stride 20: 4-quad write pattern tiles 32 banks exactly 2-way (free)
  __shared__ float zbuf[2][4][4][16][20];      // [p][kq][gate][b][col]

  // preload B fragments (U slice) into registers: 4 gates x 8 k-frags x 16B
  short8 bfr[4][8];
#pragma unroll
  for (int g = 0; g < 4; g++)
#pragma unroll
    for (int kk = 0; kk < 8; kk++) {
      int F = ((cg * 4 + kq) * 4 + g) * 8 + kk;
      bfr[g][kk] = *(const short8*)(Up + (size_t)(F * 64 + l) * 8);
    }

  float c_st = 0.0f;
  const int bl = tid >> 4;           // 0..15
  const int jj = tid & 15;
  const int bglob = mh * 16 + bl;

  // consumer base: row = batch (mh*16+lane16), k-quarter kq (dword units)
  const unsigned rowoff = (unsigned)(mh * 16 + lane16) * 1024 + (unsigned)kq * 256;
  // producer store slot (dword units, within slab)
  const unsigned stoff = (unsigned)bglob * 1024 + (unsigned)cg * 16 + jj;
  // flag poll address: lane l watches producer cg=l of team mh
  const unsigned* flgp = flags + mh * 64 + l;
  // flag publish address (block-uniform)
  unsigned* flgst = flags + mh * 64 + cg;

  // xp(0) preload (normal cached; produced by earlier dispatch)
  const unsigned short* xpbase =
      xp + (size_t)bglob * T_SZ * 4096 + (size_t)cg * 16 + jj;
  unsigned short xr0 = xpbase[0];
  unsigned short xr1 = xpbase[1024];
  unsigned short xr2 = xpbase[2048];
  unsigned short xr3 = xpbase[3072];

#pragma unroll 1
  for (int t = 0; t < T_SZ; t++) {
    // ---- consume h(t): speculative data pass, then cheap flag-gated retry ----
    const unsigned tag = (unsigned)t;
    const unsigned* hb32 = hbuf + (size_t)(t & 3) * 32768 + rowoff;
    short8 af[8];
    unsigned pend = 0xFFu;                       // wave-uniform frag bitmask
    bool first = true;
    while (pend) {
      if (!first) {
        // cheap flag gate: one coalesced dword load per pass (256 B/wave)
        while (true) {
          unsigned fl;
          asm volatile("global_load_dword %0, %1, off sc0 sc1"
                       : "=v"(fl) : "v"(flgp));
          asm volatile("s_waitcnt vmcnt(0)" ::: "memory");
          __builtin_amdgcn_sched_barrier(0);
          if (__ballot(fl < tag) == 0ull) break;
          __builtin_amdgcn_s_sleep(1);
        }
      }
      first = false;
      u32x4 ra[8], rb[8];
#pragma unroll
      for (int f = 0; f < 8; f++) {
        if (pend & (1u << f)) {
          const unsigned* p = hb32 + f * 32 + quad * 8;
          asm volatile("global_load_dwordx4 %0, %1, off sc0 sc1"
                       : "=v"(ra[f]) : "v"(p));
          asm volatile("global_load_dwordx4 %0, %1, off offset:16 sc0 sc1"
                       : "=v"(rb[f]) : "v"(p));
        }
      }
      asm volatile("s_waitcnt vmcnt(0)" ::: "memory");
      __builtin_amdgcn_sched_barrier(0);
      unsigned np = pend;
#pragma unroll
      for (int f = 0; f < 8; f++) {
        if (pend & (1u << f)) {
          u32x4 a = ra[f], b = rb[f];
          unsigned bad = ((a[0] ^ tag) | (a[1] ^ tag) | (a[2] ^ tag) | (a[3] ^ tag) |
                          (b[0] ^ tag) | (b[1] ^ tag) | (b[2] ^ tag) | (b[3] ^ tag)) & 0xFFFFu;
          if (__ballot(bad != 0u) == 0ull) {
            np &= ~(1u << f);
            u32x4 v = {(a[0] >> 16) | (a[1] & 0xFFFF0000u),
                       (a[2] >> 16) | (a[3] & 0xFFFF0000u),
                       (b[0] >> 16) | (b[1] & 0xFFFF0000u),
                       (b[2] >> 16) | (b[3] & 0xFFFF0000u)};
            af[f] = __builtin_bit_cast(short8, v);
          }
        }
      }
      pend = np;
    }

    // ---- z partial GEMM: wave kq covers k in [kq*256, kq*256+256) ----
    f32x4 acc[4];
#pragma unroll
    for (int g = 0; g < 4; g++) acc[g] = (f32x4){0.f, 0.f, 0.f, 0.f};
#pragma unroll
    for (int kk = 0; kk < 8; kk++) {
#pragma unroll
      for (int g = 0; g < 4; g++)
        acc[g] = __builtin_amdgcn_mfma_f32_16x16x32_bf16(af[kk], bfr[g][kk], acc[g], 0, 0, 0);
    }
    const int p = t & 1;
#pragma unroll
    for (int g = 0; g < 4; g++)
#pragma unroll
      for (int r = 0; r < 4; r++)
        zbuf[p][kq][g][quad * 4 + r][lane16] = acc[g][r];
    __syncthreads();                 // the ONLY barrier per step

    // ---- elementwise: thread -> (batch bl, h-col jj) ----
    float z0 = zbuf[p][0][0][bl][jj] + zbuf[p][1][0][bl][jj] + zbuf[p][2][0][bl][jj] + zbuf[p][3][0][bl][jj] + b2f(xr0);
    float z1 = zbuf[p][0][1][bl][jj] + zbuf[p][1][1][bl][jj] + zbuf[p][2][1][bl][jj] + zbuf[p][3][1][bl][jj] + b2f(xr1);
    float z2 = zbuf[p][0][2][bl][jj] + zbuf[p][1][2][bl][jj] + zbuf[p][2][2][bl][jj] + zbuf[p][3][2][bl][jj] + b2f(xr2);
    float z3 = zbuf[p][0][3][bl][jj] + zbuf[p][1][3][bl][jj] + zbuf[p][2][3][bl][jj] + zbuf[p][3][3][bl][jj] + b2f(xr3);
    float ig = sigm(z0);
    float fg = sigm(z1);
    float gg = tanh_f(z2);
    float og = sigm(z3);
    c_st = fg * c_st + ig * gg;
    float h = og * tanh_f(c_st);

    // ---- publish h(t+1): tagged dword, write-through, no ordering needed ----
    unsigned tagged = ((unsigned)f2b(h) << 16) | (unsigned)(t + 1);
    __hip_atomic_store(hbuf + (size_t)((t + 1) & 3) * 32768 + stoff, tagged,
                       __ATOMIC_RELAXED, __HIP_MEMORY_SCOPE_AGENT);
    // flag hint: this block has published step t+1 (unordered; tags validate)
    if (tid == 0)
      __hip_atomic_store(flgst, (unsigned)(t + 1),
                         __ATOMIC_RELAXED, __HIP_MEMORY_SCOPE_AGENT);

    // tail (overlaps other blocks' progress): out store + xp(t+1) prefetch
    out[((size_t)bglob * T_SZ + t) * 1024 + cg * 16 + jj] = h;
    {
      int tn = (t + 1 < T_SZ) ? t + 1 : t;
      const unsigned short* xpn = xpbase + (size_t)tn * 4096;
      xr0 = xpn[0];
      xr1 = xpn[1024];
      xr2 = xpn[2048];
      xr3 = xpn[3072];
    }
  }
}

extern "C" void kernel_launch(void* const* d_in, const int* in_sizes, int n_in,
                              void* d_out, int out_size, void* d_ws, size_t ws_size,
                              hipStream_t stream) {
  const float* X    = (const float*)d_in[0];  // [32][512][512]  f32
  const float* W    = (const float*)d_in[1];  // [512][4096]     f32
  const float* U    = (const float*)d_in[2];  // [1024][4096]    f32
  const float* bias = (const float*)d_in[3];  // [4096]          f32
  float* out = (float*)d_out;                 // [32][512][1024] f32

  char* ws = (char*)d_ws;
  unsigned short* xp    = (unsigned short*)(ws + XP_OFF);
  unsigned short* Up    = (unsigned short*)(ws + UPERM_OFF);
  unsigned short* Wp    = (unsigned short*)(ws + WPERM_OFF);
  unsigned*       hbuf  = (unsigned*)(ws + HBUF_OFF);
  unsigned*       flags = (unsigned*)(ws + FLAGS_OFF);

  hipLaunchKernelGGL(permute_U, dim3(2048), dim3(256), 0, stream, U, Up);
  hipLaunchKernelGGL(permute_W, dim3(1024), dim3(256), 0, stream, W, Wp);
  hipLaunchKernelGGL(init_hbuf, dim3(513), dim3(256), 0, stream, hbuf, flags);
  hipLaunchKernelGGL(xproj_gemm, dim3(32, 128), dim3(256), 0, stream, X, Wp, bias, xp);
  hipLaunchKernelGGL(lstm_rec, dim3(128), dim3(256), 0, stream, xp, Up, hbuf, flags, out);
}